// Round 1
// baseline (125.933 us; speedup 1.0000x reference)
//
#include <hip/hip_runtime.h>
#include <cstdint>

// Self-attention (q=k=v=x), B=4, S=4096, D=64, fp32 in/out.
// Flash-style, mfma_f32_32x32x16_bf16 with 3-term Markidis split (hi/lo bf16)
// for fp32-grade accuracy. 256 blocks x 512 threads (8 waves).
// Each block: 64 q-rows; each wave: same 64 q-rows, private 512-row KV span,
// private LDS staging (no main-loop barriers). LDS merge of 8 partials at end.

#define SB 4096
#define DDIM 64

typedef __attribute__((ext_vector_type(16))) float f32x16;
typedef __attribute__((ext_vector_type(8)))  float f32x8;
typedef __attribute__((ext_vector_type(4)))  float f32x4;
typedef __attribute__((ext_vector_type(8)))  short bf16x8;

static __device__ __forceinline__ unsigned short bf16_rne(float f) {
  union { float f; uint32_t u; } v; v.f = f;
  uint32_t u = v.u + 0x7FFFu + ((v.u >> 16) & 1u);
  return (unsigned short)(u >> 16);
}
static __device__ __forceinline__ float bf16_tof(unsigned short h) {
  union { uint32_t u; float f; } v; v.u = ((uint32_t)h) << 16;
  return v.f;
}
static __device__ __forceinline__ f32x16 MFMA(bf16x8 a, bf16x8 b, f32x16 c) {
  return __builtin_amdgcn_mfma_f32_32x32x16_bf16(a, b, c, 0, 0, 0);
}

// LDS geometry (per wave region, 17920 B):
//   K:  32 rows, stride 272 B (17x16B -> bijective bank phasing).
//       row r: hi bf16 at bytes d*2 (d=0..63), lo at 128+d*2.
//   V^T: at +8704, 64 rows (d), stride 144 B (9x16B).
//       row d: hi slots col*2 (col = chunk*16+slot, 0..31), lo at +64.
//       XOR swizzle ((d>>3)&7)<<4 on in-row byte for bank uniformity.
#define KSTRIDE 272
#define VSTRIDE 144
#define VOFF    8704
#define WREG    17920

__global__ __launch_bounds__(512, 1)
void sdpa_kernel(const float* __restrict__ x, float* __restrict__ out) {
  __shared__ __align__(16) char smem[143360];
  const int tid  = threadIdx.x;
  const int wv   = tid >> 6;
  const int lane = tid & 63;
  const int l31  = lane & 31;
  const int h5   = lane >> 5;
  const int bid  = blockIdx.x;
  const int b    = bid >> 6;
  const int q0   = (bid & 63) << 6;
  const float* __restrict__ xb = x + (size_t)b * (SB * DDIM);
  char* __restrict__ wl = smem + (size_t)wv * WREG;

  const float NEG = -3.0e38f;

  // ---- Q fragments: q rows q0 + qf*32 + l31, scaled by 1/sqrt(64)=0.125, split hi/lo ----
  bf16x8 qh[2][4], ql[2][4];
#pragma unroll
  for (int qf = 0; qf < 2; ++qf) {
#pragma unroll
    for (int dc = 0; dc < 4; ++dc) {
      const float* p = xb + (size_t)(q0 + qf * 32 + l31) * DDIM + dc * 16 + h5 * 8;
      f32x4 a = *(const f32x4*)p;
      f32x4 c = *(const f32x4*)(p + 4);
      float v[8] = {a[0], a[1], a[2], a[3], c[0], c[1], c[2], c[3]};
#pragma unroll
      for (int j = 0; j < 8; ++j) {
        float sv = v[j] * 0.125f;
        unsigned short hi = bf16_rne(sv);
        qh[qf][dc][j] = (short)hi;
        ql[qf][dc][j] = (short)bf16_rne(sv - bf16_tof(hi));
      }
    }
  }

  f32x16 ot[2][2] = {};          // O^T accumulators [qf][df]
  float mrun[2] = {NEG, NEG};
  float lrun[2] = {0.f, 0.f};

  const int kv0 = wv * (SB / 8); // 512-row private span
  const int r0  = (lane >> 3) * 4;   // 4 consecutive k-rows per lane
  const int d0g = (lane & 7) * 8;    // 8 consecutive d per lane

  // V slot-permutation constants for this lane's row group
  const int vc  = r0 >> 4;                 // chunk (16 k per mfma K-step)
  const int vko = r0 & 15;                 // {0,4,8,12}
  const int vsA = ((vko >> 2) & 1) * 8 + ((vko >> 3) & 1) * 4; // slot base
  const uint32_t vcolb = (uint32_t)(vc * 16 + vsA) * 2;

#pragma unroll 1
  for (int st = 0; st < 16; ++st) {
    const int krow0 = kv0 + st * 32;

    // ---- stage 32x64 fp32 tile -> hi/lo bf16 in private LDS ----
    bf16x8 hv[4], lv[4];
#pragma unroll
    for (int i = 0; i < 4; ++i) {
      f32x8 t = *(const f32x8*)(xb + (size_t)(krow0 + r0 + i) * DDIM + d0g);
#pragma unroll
      for (int j = 0; j < 8; ++j) {
        unsigned short hi = bf16_rne(t[j]);
        hv[i][j] = (short)hi;
        lv[i][j] = (short)bf16_rne(t[j] - bf16_tof(hi));
      }
      const int row = r0 + i;
      *(bf16x8*)(wl + row * KSTRIDE + d0g * 2)       = hv[i];
      *(bf16x8*)(wl + row * KSTRIDE + 128 + d0g * 2) = lv[i];
    }
    // V^T (slot-permuted) writes: 4 consecutive k-rows -> 4 consecutive slots
#pragma unroll
    for (int dd = 0; dd < 8; ++dd) {
      const int d = d0g + dd;
      const uint32_t sw = ((uint32_t)((d >> 3) & 7)) << 4;
      char* rb = wl + VOFF + (uint32_t)d * VSTRIDE;
      short4 pa = make_short4(hv[0][dd], hv[1][dd], hv[2][dd], hv[3][dd]);
      short4 pb = make_short4(lv[0][dd], lv[1][dd], lv[2][dd], lv[3][dd]);
      *(short4*)(rb + (vcolb ^ sw))          = pa;
      *(short4*)(rb + ((64 + vcolb) ^ sw))   = pb;
    }

    // ---- QK^T: S^T = mfma(K, Q), contraction over d (4 chunks of 16) ----
    bf16x8 kh[4], kl[4];
    {
      char* krow = wl + l31 * KSTRIDE;
#pragma unroll
      for (int dc = 0; dc < 4; ++dc) {
        const uint32_t off = (uint32_t)(dc * 32 + h5 * 16);
        kh[dc] = *(bf16x8*)(krow + off);
        kl[dc] = *(bf16x8*)(krow + 128 + off);
      }
    }
    f32x16 s0 = {}, s1 = {};
#pragma unroll
    for (int dc = 0; dc < 4; ++dc) {
      s0 = MFMA(kh[dc], qh[0][dc], s0);
      s1 = MFMA(kh[dc], qh[1][dc], s1);
      s0 = MFMA(kh[dc], ql[0][dc], s0);
      s1 = MFMA(kh[dc], ql[1][dc], s1);
      s0 = MFMA(kl[dc], qh[0][dc], s0);
      s1 = MFMA(kl[dc], qh[1][dc], s1);
    }

    // ---- online softmax (per-lane: q = l31 (+32*qf)) + P pack ----
    bf16x8 ph[2][2], pl[2][2];
#pragma unroll
    for (int qf = 0; qf < 2; ++qf) {
      f32x16 sv = qf ? s1 : s0;
      float pm = sv[0];
#pragma unroll
      for (int r = 1; r < 16; ++r) pm = fmaxf(pm, sv[r]);
      pm = fmaxf(pm, __shfl_xor(pm, 32));
      const float mnew = fmaxf(mrun[qf], pm);
      const float corr = __expf(mrun[qf] - mnew);
      mrun[qf] = mnew;
      lrun[qf] *= corr;
#pragma unroll
      for (int df = 0; df < 2; ++df)
#pragma unroll
        for (int r = 0; r < 16; ++r) ot[qf][df][r] *= corr;
      float p[16]; float ps = 0.f;
#pragma unroll
      for (int r = 0; r < 16; ++r) { p[r] = __expf(sv[r] - mnew); ps += p[r]; }
      lrun[qf] += ps;
      // reg r=8c+j of S^T holds k = 16c + sigma(8*h5+j): pack directly as B-frag
#pragma unroll
      for (int c = 0; c < 2; ++c)
#pragma unroll
        for (int j = 0; j < 8; ++j) {
          float pv = p[c * 8 + j];
          unsigned short hi = bf16_rne(pv);
          ph[qf][c][j] = (short)hi;
          pl[qf][c][j] = (short)bf16_rne(pv - bf16_tof(hi));
        }
    }

    // ---- PV: O^T += mfma(V^T, P^T), contraction over k (2 chunks of 16) ----
#pragma unroll
    for (int df = 0; df < 2; ++df) {
      const int d = df * 32 + l31;
      char* rb = wl + VOFF + (uint32_t)d * VSTRIDE;
      const uint32_t sw = ((uint32_t)((d >> 3) & 7)) << 4;
      bf16x8 vh[2], vl2[2];
#pragma unroll
      for (int c = 0; c < 2; ++c) {
        const uint32_t off = (uint32_t)(c * 32 + h5 * 16);
        vh[c]  = *(bf16x8*)(rb + (off ^ sw));
        vl2[c] = *(bf16x8*)(rb + ((64 + off) ^ sw));
      }
#pragma unroll
      for (int qf = 0; qf < 2; ++qf)
#pragma unroll
        for (int c = 0; c < 2; ++c) {
          ot[qf][df] = MFMA(vh[c],  ph[qf][c], ot[qf][df]);
          ot[qf][df] = MFMA(vh[c],  pl[qf][c], ot[qf][df]);
          ot[qf][df] = MFMA(vl2[c], ph[qf][c], ot[qf][df]);
        }
    }
  } // kv steps

#pragma unroll
  for (int qf = 0; qf < 2; ++qf) lrun[qf] += __shfl_xor(lrun[qf], 32);

  // ---- cross-wave merge of 8 KV-span partials (LDS), wave 0 finalizes ----
  __syncthreads();
  if (wv > 0) {
    char* rbase = smem + (size_t)(wv - 1) * 17408 + (size_t)lane * 272;
#pragma unroll
    for (int qf = 0; qf < 2; ++qf)
#pragma unroll
      for (int df = 0; df < 2; ++df)
#pragma unroll
        for (int t = 0; t < 4; ++t) {
          f32x4 o = { ot[qf][df][t*4+0], ot[qf][df][t*4+1],
                      ot[qf][df][t*4+2], ot[qf][df][t*4+3] };
          *(f32x4*)(rbase + (qf * 128 + df * 64 + t * 16)) = o;
        }
    f32x4 stv = { mrun[0], lrun[0], mrun[1], lrun[1] };
    *(f32x4*)(rbase + 256) = stv;
  }
  __syncthreads();
  if (wv == 0) {
#pragma unroll 1
    for (int w = 1; w < 8; ++w) {
      char* rbase = smem + (size_t)(w - 1) * 17408 + (size_t)lane * 272;
      f32x4 stv = *(f32x4*)(rbase + 256);
#pragma unroll
      for (int qf = 0; qf < 2; ++qf) {
        const float mw = stv[qf * 2 + 0];
        const float lw = stv[qf * 2 + 1];
        const float mn = fmaxf(mrun[qf], mw);
        const float f0 = __expf(mrun[qf] - mn);
        const float f1 = __expf(mw - mn);
        mrun[qf] = mn;
        lrun[qf] = lrun[qf] * f0 + lw * f1;
#pragma unroll
        for (int df = 0; df < 2; ++df)
#pragma unroll
          for (int t = 0; t < 4; ++t) {
            f32x4 o = *(f32x4*)(rbase + (qf * 128 + df * 64 + t * 16));
#pragma unroll
            for (int e = 0; e < 4; ++e)
              ot[qf][df][t*4+e] = ot[qf][df][t*4+e] * f0 + o[e] * f1;
          }
      }
    }
    // ---- store: O^T lane holds q = qf*32 + l31; d = 32*df + 8*t + 4*h5 + e ----
#pragma unroll
    for (int qf = 0; qf < 2; ++qf) {
      const float inv = 1.0f / lrun[qf];
      const size_t rowoff = ((size_t)b * SB + q0 + qf * 32 + l31) * DDIM;
#pragma unroll
      for (int df = 0; df < 2; ++df)
#pragma unroll
        for (int t = 0; t < 4; ++t) {
          const int dbase = df * 32 + t * 8 + h5 * 4;
          f32x4 o = { ot[qf][df][t*4+0] * inv, ot[qf][df][t*4+1] * inv,
                      ot[qf][df][t*4+2] * inv, ot[qf][df][t*4+3] * inv };
          *(f32x4*)(out + rowoff + dbase) = o;
        }
    }
  }
}

extern "C" void kernel_launch(void* const* d_in, const int* in_sizes, int n_in,
                              void* d_out, int out_size, void* d_ws, size_t ws_size,
                              hipStream_t stream) {
  (void)in_sizes; (void)n_in; (void)out_size; (void)d_ws; (void)ws_size;
  const float* x = (const float*)d_in[0];
  float* o = (float*)d_out;
  sdpa_kernel<<<dim3(256), dim3(512), 0, stream>>>(x, o);
}